// Round 1
// baseline (470.262 us; speedup 1.0000x reference)
//
#include <hip/hip_runtime.h>
#include <hip/hip_bf16.h>

// LSTM cell fused as one GEMM: Z[B,2048] = [input|h0] (bf16) @ Wint^T (bf16)
// Wint column order c: h_group = c>>6, gate = (c>>4)&3, h_low = c&15
//   => each wave's four 16-col MFMA subtiles are gates i,f,o,g at the SAME h,
//      so the gate nonlinearity fuses into the epilogue lane-locally.
// B=32768, E=H=512, K=E+H=1024, N=4H=2048.

#define BQ 32768
#define HQ 512
#define KK 1024
#define BH (32768 * 512)  // 16777216 elements per output

typedef __bf16 bf16x8 __attribute__((ext_vector_type(8)));
typedef float f32x4 __attribute__((ext_vector_type(4)));

__device__ __forceinline__ unsigned short f2bf(float f) {
    unsigned int u = __float_as_uint(f);
    unsigned int r = (u + 0x7fffu + ((u >> 16) & 1u)) >> 16;
    return (unsigned short)r;
}

__device__ __forceinline__ void gld_lds16(const unsigned short* g, unsigned short* l) {
    __builtin_amdgcn_global_load_lds(
        (const __attribute__((address_space(1))) void*)g,
        (__attribute__((address_space(3))) void*)l,
        16, 0, 0);
}

// ---- prepass: fp32 -> bf16 packing -----------------------------------------

__global__ __launch_bounds__(256) void pack_X(const float* __restrict__ in,
                                              const float* __restrict__ h0,
                                              unsigned short* __restrict__ Xcat) {
    const int NQ = BQ * HQ / 4;  // 4194304 quads per source
    int gi = blockIdx.x * 256 + threadIdx.x;
    const float* src;
    size_t dst;
    if (gi < NQ) {
        int e = gi * 4;
        int b = e >> 9, col = e & 511;
        src = in + e;
        dst = (size_t)b * 1024 + col;
    } else {
        int e = (gi - NQ) * 4;
        int b = e >> 9, col = e & 511;
        src = h0 + e;
        dst = (size_t)b * 1024 + 512 + col;
    }
    float4 v = *(const float4*)src;
    ushort4 o;
    o.x = f2bf(v.x); o.y = f2bf(v.y); o.z = f2bf(v.z); o.w = f2bf(v.w);
    *(ushort4*)&Xcat[dst] = o;
}

__global__ __launch_bounds__(256) void pack_W(const float* __restrict__ Wx,
                                              const float* __restrict__ Wh,
                                              const float* __restrict__ bx,
                                              const float* __restrict__ bh,
                                              unsigned short* __restrict__ Wint,
                                              float* __restrict__ biasc) {
    int j = blockIdx.x * 256 + threadIdx.x;  // 2048 rows * 256 quads
    int c = j >> 8;
    int kc = (j & 255) * 4;
    int gate = (c >> 4) & 3;
    int h = ((c >> 6) << 4) + (c & 15);
    const float* src = (kc < 512)
        ? (Wx + ((size_t)gate * 512 + h) * 512 + kc)
        : (Wh + ((size_t)gate * 512 + h) * 512 + (kc - 512));
    float4 v = *(const float4*)src;
    ushort4 o;
    o.x = f2bf(v.x); o.y = f2bf(v.y); o.z = f2bf(v.z); o.w = f2bf(v.w);
    *(ushort4*)&Wint[(size_t)c * 1024 + kc] = o;
    if ((j & 255) == 0) biasc[c] = bx[gate * 512 + h] + bh[gate * 512 + h];
}

// ---- fused GEMM + LSTM epilogue --------------------------------------------
// 128x128 tile, BK=32, 4 waves in 2x2; wave tile 64x64 = 4x4 MFMA 16x16x32.

__global__ __launch_bounds__(256) void lstm_gemm(const unsigned short* __restrict__ Xcat,
                                                 const unsigned short* __restrict__ Wint,
                                                 const float* __restrict__ biasc,
                                                 const float* __restrict__ c0,
                                                 float* __restrict__ out) {
    __shared__ __align__(16) unsigned short ldsA[128 * 32];
    __shared__ __align__(16) unsigned short ldsB[128 * 32];

    const int tid = threadIdx.x;
    const int lane = tid & 63;
    const int wave = tid >> 6;
    const int wm = wave >> 1;   // 0..1 (row of wave grid)
    const int wn = wave & 1;    // 0..1 (col of wave grid)
    const int quad = lane >> 4; // 0..3
    const int lrow = lane & 15; // 0..15
    const int koff = quad * 8;

    const int bn = blockIdx.x;          // 0..15
    const int bm = blockIdx.y;          // 0..255
    const int m0 = bm * 128;
    const int n0 = bn * 128;

    // staging: thread t stages 16B (8 bf16); pass p adds 64 rows
    const int arow = tid >> 2;          // 0..63
    const int acol = (tid & 3) * 8;     // 0,8,16,24

    f32x4 acc[4][4];
    for (int i = 0; i < 4; i++)
        for (int j = 0; j < 4; j++) {
            f32x4 z = {0.f, 0.f, 0.f, 0.f};
            acc[i][j] = z;
        }

    const unsigned short* gA = Xcat + (size_t)(m0 + arow) * KK + acol;
    const unsigned short* gB = Wint + (size_t)(n0 + arow) * KK + acol;

    for (int kt = 0; kt < KK; kt += 32) {
        gld_lds16(gA + kt, &ldsA[tid * 8]);
        gld_lds16(gA + (size_t)64 * KK + kt, &ldsA[2048 + tid * 8]);
        gld_lds16(gB + kt, &ldsB[tid * 8]);
        gld_lds16(gB + (size_t)64 * KK + kt, &ldsB[2048 + tid * 8]);
        __syncthreads();

        bf16x8 af[4], bfr[4];
        for (int mi = 0; mi < 4; mi++)
            af[mi] = *(const bf16x8*)&ldsA[(wm * 64 + mi * 16 + lrow) * 32 + koff];
        for (int ni = 0; ni < 4; ni++)
            bfr[ni] = *(const bf16x8*)&ldsB[(wn * 64 + ni * 16 + lrow) * 32 + koff];
        for (int mi = 0; mi < 4; mi++)
            for (int ni = 0; ni < 4; ni++)
                acc[mi][ni] = __builtin_amdgcn_mfma_f32_16x16x32_bf16(
                    af[mi], bfr[ni], acc[mi][ni], 0, 0, 0);
        __syncthreads();
    }

    // epilogue: lane owns gates i,f,o,g (ni=0..3) at h fixed per lane
    float bi[4];
    for (int ni = 0; ni < 4; ni++)
        bi[ni] = biasc[n0 + wn * 64 + ni * 16 + lrow];
    const int h = (bn * 2 + wn) * 16 + lrow;

    for (int mi = 0; mi < 4; mi++) {
        for (int r = 0; r < 4; r++) {
            int b = m0 + wm * 64 + mi * 16 + quad * 4 + r;
            float zi = acc[mi][0][r] + bi[0];
            float zf = acc[mi][1][r] + bi[1];
            float zo = acc[mi][2][r] + bi[2];
            float zg = acc[mi][3][r] + bi[3];
            float ig = 1.f / (1.f + __expf(-zi));
            float fg = 1.f / (1.f + __expf(-zf));
            float og = 1.f / (1.f + __expf(-zo));
            float gg = 1.f - 2.f / (__expf(2.f * zg) + 1.f);  // tanh, stable both ends
            float c0v = c0[(size_t)b * HQ + h];
            float c1 = fg * c0v + ig * gg;
            float th = 1.f - 2.f / (__expf(2.f * c1) + 1.f);
            out[(size_t)b * HQ + h] = og * th;                 // h1
            out[(size_t)BH + (size_t)b * HQ + h] = c1;         // c1
        }
    }
}

extern "C" void kernel_launch(void* const* d_in, const int* in_sizes, int n_in,
                              void* d_out, int out_size, void* d_ws, size_t ws_size,
                              hipStream_t stream) {
    (void)in_sizes; (void)n_in; (void)out_size; (void)ws_size;
    const float* input = (const float*)d_in[0];
    const float* h0    = (const float*)d_in[1];
    const float* c0    = (const float*)d_in[2];
    const float* Wx    = (const float*)d_in[3];
    const float* bx    = (const float*)d_in[4];
    const float* Wh    = (const float*)d_in[5];
    const float* bh    = (const float*)d_in[6];
    float* out = (float*)d_out;

    char* ws = (char*)d_ws;
    unsigned short* Xcat = (unsigned short*)ws;                     // 64 MiB
    unsigned short* Wint = (unsigned short*)(ws + (size_t)67108864); // 4 MiB
    float* biasc = (float*)(ws + (size_t)71303168);                  // 8 KiB

    pack_X<<<32768, 256, 0, stream>>>(input, h0, Xcat);
    pack_W<<<2048, 256, 0, stream>>>(Wx, Wh, bx, bh, Wint, biasc);
    lstm_gemm<<<dim3(16, 256), 256, 0, stream>>>(Xcat, Wint, biasc, c0, out);
}